// Round 2
// baseline (302.243 us; speedup 1.0000x reference)
//
#include <hip/hip_runtime.h>

// adaptive_aggregationPC: out[b,0,h,w] = sum_{dh,dw} sal[b, h+dh-2, w+dw-2] * agg[b, dh*5+dw, h, w]
// where sal = max(input_thick, input_thin), zero padding. B=8, H=W=512, fp32.
// Memory-bound: ~224 MiB compulsory traffic -> ~37us floor at 6.3 TB/s.

constexpr int K = 5;
constexpr int PAD = 2;

__global__ __launch_bounds__(256) void adaptive_agg_kernel(
    const float* __restrict__ thick,
    const float* __restrict__ thin,
    const float* __restrict__ agg,
    float* __restrict__ out,
    int B, int H, int W)
{
    const int wq = W >> 2;                       // float4 groups per row
    int tid = blockIdx.x * blockDim.x + threadIdx.x;
    int w0 = (tid % wq) << 2;                    // first of 4 pixels
    int h  = (tid / wq) % H;
    int b  = tid / (wq * H);
    if (b >= B) return;

    const size_t plane = (size_t)H * W;
    const float* tk  = thick + (size_t)b * plane;
    const float* tn  = thin  + (size_t)b * plane;
    const float* ag0 = agg + (size_t)b * (K * K) * plane + (size_t)h * W + w0;

    float acc0 = 0.f, acc1 = 0.f, acc2 = 0.f, acc3 = 0.f;

    #pragma unroll
    for (int dh = 0; dh < K; ++dh) {
        int hh = h + dh - PAD;
        // sal window for this row: indices j=0..11 hold sal at w = w0-4+j
        // pixels p=0..3 with offset dw need j = p + dw + 2  (range 2..9)
        float srow[12];
        if (hh < 0 || hh >= H) {
            #pragma unroll
            for (int j = 0; j < 12; ++j) srow[j] = 0.f;
        } else {
            const float* tkr = tk + (size_t)hh * W;
            const float* tnr = tn + (size_t)hh * W;
            if (w0 >= 4 && w0 + 8 <= W) {
                // interior fast path: 3 aligned float4 loads each (w0-4, w0, w0+4)
                float4 a0 = *(const float4*)(tkr + w0 - 4);
                float4 a1 = *(const float4*)(tkr + w0);
                float4 a2 = *(const float4*)(tkr + w0 + 4);
                float4 c0 = *(const float4*)(tnr + w0 - 4);
                float4 c1 = *(const float4*)(tnr + w0);
                float4 c2 = *(const float4*)(tnr + w0 + 4);
                srow[0]  = fmaxf(a0.x, c0.x); srow[1]  = fmaxf(a0.y, c0.y);
                srow[2]  = fmaxf(a0.z, c0.z); srow[3]  = fmaxf(a0.w, c0.w);
                srow[4]  = fmaxf(a1.x, c1.x); srow[5]  = fmaxf(a1.y, c1.y);
                srow[6]  = fmaxf(a1.z, c1.z); srow[7]  = fmaxf(a1.w, c1.w);
                srow[8]  = fmaxf(a2.x, c2.x); srow[9]  = fmaxf(a2.y, c2.y);
                srow[10] = fmaxf(a2.z, c2.z); srow[11] = fmaxf(a2.w, c2.w);
            } else {
                // edge threads (w0==0 or w0==W-4): predicated scalar loads
                #pragma unroll
                for (int j = 0; j < 12; ++j) {
                    int ww = w0 - 4 + j;
                    srow[j] = (ww >= 0 && ww < W) ? fmaxf(tkr[ww], tnr[ww]) : 0.f;
                }
            }
        }
        const float* ag = ag0 + (size_t)(dh * K) * plane;
        #pragma unroll
        for (int dw = 0; dw < K; ++dw) {
            float4 cv = *(const float4*)(ag + (size_t)dw * plane);
            acc0 = fmaf(cv.x, srow[2 + dw + 0], acc0);
            acc1 = fmaf(cv.y, srow[2 + dw + 1], acc1);
            acc2 = fmaf(cv.z, srow[2 + dw + 2], acc2);
            acc3 = fmaf(cv.w, srow[2 + dw + 3], acc3);
        }
    }

    *(float4*)(out + (size_t)b * plane + (size_t)h * W + w0) =
        make_float4(acc0, acc1, acc2, acc3);
}

extern "C" void kernel_launch(void* const* d_in, const int* in_sizes, int n_in,
                              void* d_out, int out_size, void* d_ws, size_t ws_size,
                              hipStream_t stream) {
    const float* thick = (const float*)d_in[0];
    const float* thin  = (const float*)d_in[1];
    const float* agg   = (const float*)d_in[2];
    float* out = (float*)d_out;

    const int H = 512, W = 512;
    const int B = in_sizes[0] / (H * W);   // = 8

    int total = B * H * (W / 4);           // one thread per 4 output pixels
    int block = 256;
    int grid = (total + block - 1) / block;
    adaptive_agg_kernel<<<grid, block, 0, stream>>>(thick, thin, agg, out, B, H, W);
}

// Round 4
// 293.008 us; speedup vs baseline: 1.0315x; 1.0315x over previous
//
#include <hip/hip_runtime.h>

// adaptive_aggregationPC: out[b,0,h,w] = sum_{dh,dw} sal[b, h+dh-2, w+dw-2] * agg[b, dh*5+dw, h, w]
// sal = max(thick, thin), zero padding. B=8, H=W=512, fp32.
// Memory-bound: ~224 MiB compulsory -> ~37us kernel floor at 6.3 TB/s.
// R2 lesson: every wave hit the divergent edge path (+120 masked VMEM insts/wave).
// R3: branch-free halo (clamped aligned loads + select-zero), 8 px/thread
// (1 wave == 1 row, uniform h), nontemporal agg/out.
// R4: nontemporal builtins need clang ext_vector_type, not HIP_vector_type.

constexpr int K = 5;
constexpr int PAD = 2;

typedef float vfloat4 __attribute__((ext_vector_type(4)));

__global__ __launch_bounds__(256) void adaptive_agg_kernel(
    const float* __restrict__ thick,
    const float* __restrict__ thin,
    const float* __restrict__ agg,
    float* __restrict__ out,
    int B, int H, int W)
{
    const int wq = W >> 3;                       // 8-pixel groups per row (=64: one wave per row)
    int tid = blockIdx.x * blockDim.x + threadIdx.x;
    int w0 = (tid % wq) << 3;                    // first of 8 pixels
    int h  = (tid / wq) % H;
    int b  = tid / (wq * H);
    if (b >= B) return;

    const size_t plane = (size_t)H * W;
    const float* tk  = thick + (size_t)b * plane;
    const float* tn  = thin  + (size_t)b * plane;
    const float* ag0 = agg + (size_t)b * (K * K) * plane + (size_t)h * W + w0;

    float acc[8];
    #pragma unroll
    for (int p = 0; p < 8; ++p) acc[p] = 0.f;

    // clamped, always-16B-aligned window load addresses
    const int a0 = (w0 >= 4) ? (w0 - 4) : 0;                 // only lane 0 clamps
    const int a3 = (w0 + 8 <= W - 4) ? (w0 + 8) : (W - 4);   // only last lane clamps

    #pragma unroll
    for (int dh = 0; dh < K; ++dh) {
        int hh = h + dh - PAD;
        if (hh < 0 || hh >= H) continue;   // wave-uniform; OOB rows contribute exact 0
        const float* tkr = tk + (size_t)hh * W;
        const float* tnr = tn + (size_t)hh * W;

        vfloat4 t0 = *(const vfloat4*)(tkr + a0);
        vfloat4 t1 = *(const vfloat4*)(tkr + w0);
        vfloat4 t2 = *(const vfloat4*)(tkr + w0 + 4);
        vfloat4 t3 = *(const vfloat4*)(tkr + a3);
        vfloat4 n0 = *(const vfloat4*)(tnr + a0);
        vfloat4 n1 = *(const vfloat4*)(tnr + w0);
        vfloat4 n2 = *(const vfloat4*)(tnr + w0 + 4);
        vfloat4 n3 = *(const vfloat4*)(tnr + a3);

        // srow[j] = sal at w = w0-4+j, j=0..15; pixels p with offset dw use j = p+dw+2 (2..13)
        float srow[16];
        #pragma unroll
        for (int e = 0; e < 4; ++e) {
            srow[0 + e]  = fmaxf(t0[e], n0[e]);
            srow[4 + e]  = fmaxf(t1[e], n1[e]);
            srow[8 + e]  = fmaxf(t2[e], n2[e]);
            srow[12 + e] = fmaxf(t3[e], n3[e]);
        }
        // branch-free halo zeroing (only lanes 0 / 63 have any OOB j)
        #pragma unroll
        for (int j = 0; j < 16; ++j) {
            int ww = w0 - 4 + j;
            srow[j] = (ww >= 0 && ww < W) ? srow[j] : 0.f;
        }

        const float* ag = ag0 + (size_t)(dh * K) * plane;
        #pragma unroll
        for (int dw = 0; dw < K; ++dw) {
            const float* ap = ag + (size_t)dw * plane;
            vfloat4 c0 = __builtin_nontemporal_load((const vfloat4*)ap);
            vfloat4 c1 = __builtin_nontemporal_load((const vfloat4*)(ap + 4));
            #pragma unroll
            for (int e = 0; e < 4; ++e) {
                acc[e]     = fmaf(c0[e], srow[2 + dw + e],     acc[e]);
                acc[4 + e] = fmaf(c1[e], srow[2 + dw + 4 + e], acc[4 + e]);
            }
        }
    }

    float* op = out + (size_t)b * plane + (size_t)h * W + w0;
    vfloat4 o0 = { acc[0], acc[1], acc[2], acc[3] };
    vfloat4 o1 = { acc[4], acc[5], acc[6], acc[7] };
    __builtin_nontemporal_store(o0, (vfloat4*)op);
    __builtin_nontemporal_store(o1, (vfloat4*)(op + 4));
}

extern "C" void kernel_launch(void* const* d_in, const int* in_sizes, int n_in,
                              void* d_out, int out_size, void* d_ws, size_t ws_size,
                              hipStream_t stream) {
    const float* thick = (const float*)d_in[0];
    const float* thin  = (const float*)d_in[1];
    const float* agg   = (const float*)d_in[2];
    float* out = (float*)d_out;

    const int H = 512, W = 512;
    const int B = in_sizes[0] / (H * W);   // = 8

    int total = B * H * (W / 8);           // one thread per 8 output pixels
    int block = 256;
    int grid = (total + block - 1) / block;
    adaptive_agg_kernel<<<grid, block, 0, stream>>>(thick, thin, agg, out, B, H, W);
}